// Round 9
// baseline (215.326 us; speedup 1.0000x reference)
//
#include <hip/hip_runtime.h>
#include <math.h>

// B=8, N=1024, D=128.  kv[b,n,512] = [k_mu | v_mu | k_sigma | v_sigma]
// 2-kernel plan (transposed GEMM, j-split 2, fused last-block tail):
//  1) prepass: round fp32 -> bf16 into MFMA-fragment order:
//     frag[side][b][tile16][kc][arr][512 ush], chunk = 64 lanes x 8 bf16.
//     side0 = K (cols 0/256), side1 = V (cols 128/384); arr 0=mu 1=sg.
//     Zeroes acc+counters in ws; seeds the 8 log-prob slots with LPCONST.
//  2) actor: S^T = V.K^T per 16-i tile (A-frag = V rows = j, B-frag = K
//     rows = i). C[row=j][col=i]: lane's col is a fixed i, its 4 regs are
//     4 j's -> j-weighted geometric sum folds in-register. Grid (64 itx,
//     2 jh, 8 b) = 1024 blocks x 8 waves = 4 blocks/CU = 32 waves/CU (max
//     occupancy - the kernel is latency-bound, R7/R8 evidence). Each wave
//     covers 64 j (4 jt). j-halves merge via atomicAdd into ws acc; a
//     per-(b,itx) counter elects the last block to run the tanh-normal
//     tail inline (R5-proven pattern). pos staged in LDS.
// NOTE: no __launch_bounds__ min-waves arg (R5: (256,4) => 64-VGPR clamp,
// 100 MB scratch spill). Plain bf16 is accuracy-safe: absmax 4096 identical
// for fp32 / split-bf16 / bf16 runs (accumulation-order noise dominates).

#define NTOK 1024
#define LPCONST 14147.0828114f   // -3072*ln(0.01)

typedef __bf16 bf16x8 __attribute__((ext_vector_type(8)));
typedef float f32x4 __attribute__((ext_vector_type(4)));
#define MFMA(a, b, c) __builtin_amdgcn_mfma_f32_16x16x32_bf16(a, b, c, 0, 0, 0)

__device__ __forceinline__ unsigned short to_bf16(float x) {
    return (unsigned short)((__float_as_uint(x) + 0x8000u) >> 16);
}

template <int CTRL>
__device__ __forceinline__ float dpp_add(float v) {
    int y = __builtin_amdgcn_update_dpp(0, __float_as_int(v), CTRL, 0xf, 0xf, true);
    return v + __int_as_float(y);
}
__device__ __forceinline__ float red16(float v) {
    v = dpp_add<0xB1>(v);    // xor1 within quad
    v = dpp_add<0x4E>(v);    // xor2 within quad
    v = dpp_add<0x141>(v);   // row_half_mirror
    v = dpp_add<0x140>(v);   // row_mirror
    return v;
}

__device__ __forceinline__ float softplusf(float z) {
    return z > 20.f ? z : log1pf(expf(z));
}

// ---------------- prepass ----------------
__global__ __launch_bounds__(256) void prepass_kernel(
    const float* __restrict__ kv, unsigned short* __restrict__ frag,
    float* __restrict__ acc, unsigned int* __restrict__ counters,
    float* __restrict__ out)
{
    const int t = blockIdx.x * 256 + threadIdx.x;   // 0..262143
    if (t < 8 * NTOK * 6) acc[t] = 0.f;             // zero merge accumulators
    if (t < 512) counters[t] = 0u;                  // zero completion counters
    if (t < 8) out[8 * NTOK * 3 + t] = LPCONST;     // seed log-prob slots

    const int lane = t & 63;
    const int kc   = (t >> 6) & 3;
    const int tile = (t >> 8) & 63;
    const int b    = (t >> 14) & 7;
    const int side = t >> 17;

    const int row = tile * 16 + (lane & 15);
    const int kof = kc * 32 + (lane >> 4) * 8;
    const float* gp = kv + ((size_t)b * NTOK + row) * 512 + side * 128 + kof;
    const float4 m0 = *(const float4*)gp;
    const float4 m1 = *(const float4*)(gp + 4);
    const float4 s0 = *(const float4*)(gp + 256);
    const float4 s1 = *(const float4*)(gp + 260);

    unsigned short* cp = frag + (size_t)side * 2097152 +
                         (size_t)(b * 64 + tile) * 4096 + kc * 1024 + lane * 8;
    ushort4 h0, h1;
    h0.x = to_bf16(m0.x); h0.y = to_bf16(m0.y); h0.z = to_bf16(m0.z); h0.w = to_bf16(m0.w);
    h1.x = to_bf16(m1.x); h1.y = to_bf16(m1.y); h1.z = to_bf16(m1.z); h1.w = to_bf16(m1.w);
    *(ushort4*)(cp + 0) = h0; *(ushort4*)(cp + 4) = h1;       // arr0 mu
    h0.x = to_bf16(s0.x); h0.y = to_bf16(s0.y); h0.z = to_bf16(s0.z); h0.w = to_bf16(s0.w);
    h1.x = to_bf16(s1.x); h1.y = to_bf16(s1.y); h1.z = to_bf16(s1.z); h1.w = to_bf16(s1.w);
    *(ushort4*)(cp + 512) = h0; *(ushort4*)(cp + 516) = h1;   // arr1 sg
}

// ---------------- fused gemm^T + geometry + merge + tail ----------------
__global__ __launch_bounds__(512) void actor_kernel(
    const unsigned short* __restrict__ frag, const float* __restrict__ pos,
    const float* __restrict__ eps, float* __restrict__ acc,
    unsigned int* __restrict__ counters, float* __restrict__ out)
{
    const int t = threadIdx.x;
    const int w = t >> 6;        // wave 0..7
    const int lane = t & 63;
    const int q = lane >> 4;
    const int r16 = lane & 15;
    const int itx = blockIdx.x;  // i-tile 0..63
    const int jh  = blockIdx.y;  // j-half 0..1
    const int b   = blockIdx.z;
    const int i0 = itx * 16;

    const unsigned short* fragK = frag;             // side 0
    const unsigned short* fragV = frag + 2097152;   // side 1
    const float* posb = pos + (size_t)b * NTOK * 3;

    __shared__ float spos[NTOK * 3];     // 12 KB
    __shared__ float wacc[8 * 16 * 6];   // 3 KB
    __shared__ unsigned int is_last;

    // ---- stage all positions for this batch into LDS (coalesced) ----
    #pragma unroll
    for (int u = t; u < 768; u += 512)
        *(float4*)&spos[u * 4] = *(const float4*)&posb[u * 4];

    // ---- preload K (B-operand) frags for this i-tile: 32 VGPRs ----
    const unsigned short* kp = fragK + (size_t)(b * 64 + itx) * 4096 + lane * 8;
    bf16x8 Km[4], Ks[4];
    #pragma unroll
    for (int kc = 0; kc < 4; ++kc) {
        Km[kc] = *(const bf16x8*)(kp + kc * 1024);
        Ks[kc] = *(const bf16x8*)(kp + kc * 1024 + 512);
    }

    __syncthreads();

    // lane's i (C column) is fixed
    const int i = i0 + r16;
    const float pix = spos[i * 3 + 0];
    const float piy = spos[i * 3 + 1];
    const float piz = spos[i * 3 + 2];

    float am0 = 0.f, am1 = 0.f, am2 = 0.f;
    float al0 = 0.f, al1 = 0.f, al2 = 0.f;

    const int jtile0 = jh * 32 + w * 4;   // this wave's first 16-j tile
    const unsigned short* vbase =
        fragV + (size_t)(b * 64 + jtile0) * 4096 + lane * 8;

    #pragma unroll
    for (int jt = 0; jt < 4; ++jt) {
        const unsigned short* vp = vbase + jt * 4096;
        f32x4 accm = (f32x4){0.f, 0.f, 0.f, 0.f};
        f32x4 accs = (f32x4){0.f, 0.f, 0.f, 0.f};
        #pragma unroll
        for (int kc = 0; kc < 4; ++kc) {
            const bf16x8 Vm = *(const bf16x8*)(vp + kc * 1024);
            const bf16x8 Vs = *(const bf16x8*)(vp + kc * 1024 + 512);
            accm = MFMA(Vm, Km[kc], accm);   // C[row=j][col=i]
            accs = MFMA(Vs, Ks[kc], accs);
        }
        // ---- fold this tile's 4 j's (rows q*4+reg) into per-i sums ----
        const int jbase = (jtile0 + jt) * 16 + q * 4;
        #pragma unroll
        for (int reg = 0; reg < 4; ++reg) {
            const float* pj = &spos[(jbase + reg) * 3];  // LDS broadcast
            const float dx = pix - pj[0];
            const float dy = piy - pj[1];
            const float dz = piz - pj[2];
            const float d2 = dx * dx + dy * dy + dz * dz;
            const float inv = d2 > 0.f ? rsqrtf(d2) : 0.f;   // i==j -> 0, matches ref
            const float wm = accm[reg] * inv;
            const float ws = accs[reg] * inv;
            am0 = fmaf(dx, wm, am0); am1 = fmaf(dy, wm, am1); am2 = fmaf(dz, wm, am2);
            al0 = fmaf(dx, ws, al0); al1 = fmaf(dy, ws, al1); al2 = fmaf(dz, ws, al2);
        }
    }

    // ---- reduce over the 4 q-groups ----
    am0 += __shfl_xor(am0, 16, 64); am0 += __shfl_xor(am0, 32, 64);
    am1 += __shfl_xor(am1, 16, 64); am1 += __shfl_xor(am1, 32, 64);
    am2 += __shfl_xor(am2, 16, 64); am2 += __shfl_xor(am2, 32, 64);
    al0 += __shfl_xor(al0, 16, 64); al0 += __shfl_xor(al0, 32, 64);
    al1 += __shfl_xor(al1, 16, 64); al1 += __shfl_xor(al1, 32, 64);
    al2 += __shfl_xor(al2, 16, 64); al2 += __shfl_xor(al2, 32, 64);

    // ---- cross-wave combine via LDS ----
    if (lane < 16) {
        float* p = wacc + (w * 16 + r16) * 6;
        p[0] = am0; p[1] = am1; p[2] = am2; p[3] = al0; p[4] = al1; p[5] = al2;
    }
    __syncthreads();

    // ---- merge the block's 16x6 result into the global accumulator ----
    float* accb = acc + ((size_t)b * NTOK + i0) * 6;
    if (t < 96) {
        float v = 0.f;
        #pragma unroll
        for (int ww = 0; ww < 8; ++ww) v += wacc[ww * 96 + t];
        atomicAdd(accb + t, v);
        __threadfence();   // make the adds device-visible before the signal
    }
    __syncthreads();
    if (t == 0)
        is_last = (atomicAdd(&counters[b * 64 + itx], 1u) == 1u);
    __syncthreads();

    // ---- last block for (b,itx): inline tanh-normal tail for 16 rows ----
    if (is_last) {
        __threadfence();
        if (t < 16) {
            const int gi = b * NTOK + i0 + t;
            float* ap = accb + t * 6;
            float vals[6];
            #pragma unroll
            for (int c = 0; c < 6; ++c) vals[c] = atomicAdd(ap + c, 0.f);  // coherent read
            float lp = 0.f;
            #pragma unroll
            for (int c = 0; c < 3; ++c) {
                const float als = fminf(fmaxf(vals[3 + c], -20.f), 2.f);
                const float sd = expf(als);
                const float e = eps[gi * 3 + c];
                const float pre = fmaf(sd, e, vals[c]);
                out[gi * 3 + c] = tanhf(pre) * 0.01f;
                const float t2 = 2.f * pre;
                lp += -0.5f * e * e - als - 2.3052328944f + softplusf(t2) + softplusf(-t2);
            }
            lp = red16(lp);   // lanes 0..15 hold the 16 rows
            if (t == 0) atomicAdd(out + 8 * NTOK * 3 + b, lp);
        }
    }
}

extern "C" void kernel_launch(void* const* d_in, const int* in_sizes, int n_in,
                              void* d_out, int out_size, void* d_ws, size_t ws_size,
                              hipStream_t stream) {
    const float* kv = (const float*)d_in[0];
    const float* pos = (const float*)d_in[1];
    const float* eps = (const float*)d_in[2];
    float* out = (float*)d_out;
    unsigned short* frag = (unsigned short*)d_ws;                        // 8 MiB
    float* acc = (float*)((char*)d_ws + 8388608);                        // 192 KiB
    unsigned int* counters = (unsigned int*)((char*)d_ws + 8585216);     // 2 KiB

    prepass_kernel<<<dim3(1024), 256, 0, stream>>>(kv, frag, acc, counters, out);
    actor_kernel<<<dim3(64, 2, 8), 512, 0, stream>>>(frag, pos, eps, acc, counters, out);
}

// Round 10
// 92.722 us; speedup vs baseline: 2.3223x; 2.3223x over previous
//
#include <hip/hip_runtime.h>
#include <math.h>

// B=8, N=1024, D=128.  kv[b,n,512] = [k_mu | v_mu | k_sigma | v_sigma]
// 2-kernel plan (transposed GEMM, fused tail, LDS pos, XCD swizzle):
//  1) prepass: round fp32 -> bf16 into MFMA-fragment order:
//     frag[side][b][tile16][kc][arr][512 ush], chunk = 64 lanes x 8 bf16.
//     side0 = K (cols 0/256), side1 = V (cols 128/384); arr 0=mu 1=sg.
//     Seeds the 8 log-prob slots of out with LPCONST.
//  2) actor: S^T = V.K^T per 16-i tile (A-frag = V rows = j, B-frag = K
//     rows = i). C[row=j][col=i]: lane's col is a fixed i, its 4 regs are
//     4 j's -> j-weighted geometric sum folds in-register. Block = 512 thr
//     (8 waves x 128 j) covers ALL j for its 16 i -> no partials, tail
//     inline. pos staged in LDS. Grid = 512 blocks, 1-D, with
//     b = blockIdx.x & 7 so (heuristic round-robin dispatch) XCD k gets
//     only batch-k blocks -> per-XCD V working set 520 KB < 4 MiB L2.
//     R7/R8 evidence: without the swizzle each XCD mixes all 8 batches
//     (4.2 MB > L2) and every V-frag read goes to L3 => ~38 us actor.
// NOTE: no __launch_bounds__ min-waves arg (R5: 64-VGPR clamp + spill).
// NOTE: no __threadfence / cross-block atomic merge (R9: wbl2 storms
// flush L2 and serialize the whole grid; 150 us).
// Plain bf16 is accuracy-safe: absmax 4096 identical for fp32 /
// split-bf16 / bf16 runs (accumulation-order noise dominates).

#define NTOK 1024
#define LPCONST 14147.0828114f   // -3072*ln(0.01)

typedef __bf16 bf16x8 __attribute__((ext_vector_type(8)));
typedef float f32x4 __attribute__((ext_vector_type(4)));
#define MFMA(a, b, c) __builtin_amdgcn_mfma_f32_16x16x32_bf16(a, b, c, 0, 0, 0)

__device__ __forceinline__ unsigned short to_bf16(float x) {
    return (unsigned short)((__float_as_uint(x) + 0x8000u) >> 16);
}

template <int CTRL>
__device__ __forceinline__ float dpp_add(float v) {
    int y = __builtin_amdgcn_update_dpp(0, __float_as_int(v), CTRL, 0xf, 0xf, true);
    return v + __int_as_float(y);
}
__device__ __forceinline__ float red16(float v) {
    v = dpp_add<0xB1>(v);    // xor1 within quad
    v = dpp_add<0x4E>(v);    // xor2 within quad
    v = dpp_add<0x141>(v);   // row_half_mirror
    v = dpp_add<0x140>(v);   // row_mirror
    return v;
}

__device__ __forceinline__ float softplusf(float z) {
    return z > 20.f ? z : log1pf(expf(z));
}

// ---------------- prepass ----------------
__global__ __launch_bounds__(256) void prepass_kernel(
    const float* __restrict__ kv, unsigned short* __restrict__ frag,
    float* __restrict__ out)
{
    const int t = blockIdx.x * 256 + threadIdx.x;   // 0..262143
    if (t < 8) out[8 * NTOK * 3 + t] = LPCONST;     // seed log-prob slots

    const int lane = t & 63;
    const int kc   = (t >> 6) & 3;
    const int tile = (t >> 8) & 63;
    const int b    = (t >> 14) & 7;
    const int side = t >> 17;

    const int row = tile * 16 + (lane & 15);
    const int kof = kc * 32 + (lane >> 4) * 8;
    const float* gp = kv + ((size_t)b * NTOK + row) * 512 + side * 128 + kof;
    const float4 m0 = *(const float4*)gp;
    const float4 m1 = *(const float4*)(gp + 4);
    const float4 s0 = *(const float4*)(gp + 256);
    const float4 s1 = *(const float4*)(gp + 260);

    unsigned short* cp = frag + (size_t)side * 2097152 +
                         (size_t)(b * 64 + tile) * 4096 + kc * 1024 + lane * 8;
    ushort4 h0, h1;
    h0.x = to_bf16(m0.x); h0.y = to_bf16(m0.y); h0.z = to_bf16(m0.z); h0.w = to_bf16(m0.w);
    h1.x = to_bf16(m1.x); h1.y = to_bf16(m1.y); h1.z = to_bf16(m1.z); h1.w = to_bf16(m1.w);
    *(ushort4*)(cp + 0) = h0; *(ushort4*)(cp + 4) = h1;       // arr0 mu
    h0.x = to_bf16(s0.x); h0.y = to_bf16(s0.y); h0.z = to_bf16(s0.z); h0.w = to_bf16(s0.w);
    h1.x = to_bf16(s1.x); h1.y = to_bf16(s1.y); h1.z = to_bf16(s1.z); h1.w = to_bf16(s1.w);
    *(ushort4*)(cp + 512) = h0; *(ushort4*)(cp + 516) = h1;   // arr1 sg
}

// ---------------- fused gemm^T + geometry + tail ----------------
__global__ __launch_bounds__(512) void actor_kernel(
    const unsigned short* __restrict__ frag, const float* __restrict__ pos,
    const float* __restrict__ eps, float* __restrict__ out)
{
    const int t = threadIdx.x;
    const int w = t >> 6;        // wave 0..7 -> j range [w*128, w*128+128)
    const int lane = t & 63;
    const int q = lane >> 4;
    const int r16 = lane & 15;
    const int b   = blockIdx.x & 7;    // XCD-local batch (round-robin heuristic)
    const int itx = blockIdx.x >> 3;   // i-tile 0..63
    const int i0 = itx * 16;

    const unsigned short* fragK = frag;             // side 0
    const unsigned short* fragV = frag + 2097152;   // side 1
    const float* posb = pos + (size_t)b * NTOK * 3;

    __shared__ float spos[NTOK * 3];     // 12 KB
    __shared__ float wacc[8 * 16 * 6];   // 3 KB
    __shared__ float fin[96];

    // ---- stage all positions for this batch into LDS (coalesced) ----
    #pragma unroll
    for (int u = t; u < 768; u += 512)
        *(float4*)&spos[u * 4] = *(const float4*)&posb[u * 4];

    // ---- preload K (B-operand) frags for this i-tile: 32 VGPRs ----
    const unsigned short* kp = fragK + (size_t)(b * 64 + itx) * 4096 + lane * 8;
    bf16x8 Km[4], Ks[4];
    #pragma unroll
    for (int kc = 0; kc < 4; ++kc) {
        Km[kc] = *(const bf16x8*)(kp + kc * 1024);
        Ks[kc] = *(const bf16x8*)(kp + kc * 1024 + 512);
    }

    __syncthreads();

    // lane's i (C column) is fixed
    const int i = i0 + r16;
    const float pix = spos[i * 3 + 0];
    const float piy = spos[i * 3 + 1];
    const float piz = spos[i * 3 + 2];

    float am0 = 0.f, am1 = 0.f, am2 = 0.f;
    float al0 = 0.f, al1 = 0.f, al2 = 0.f;

    const unsigned short* vbase =
        fragV + (size_t)(b * 64 + w * 8) * 4096 + lane * 8;

    #pragma unroll 2
    for (int jt = 0; jt < 8; ++jt) {
        const unsigned short* vp = vbase + jt * 4096;
        f32x4 accm = (f32x4){0.f, 0.f, 0.f, 0.f};
        f32x4 accs = (f32x4){0.f, 0.f, 0.f, 0.f};
        #pragma unroll
        for (int kc = 0; kc < 4; ++kc) {
            const bf16x8 Vm = *(const bf16x8*)(vp + kc * 1024);
            const bf16x8 Vs = *(const bf16x8*)(vp + kc * 1024 + 512);
            accm = MFMA(Vm, Km[kc], accm);   // C[row=j][col=i]
            accs = MFMA(Vs, Ks[kc], accs);
        }
        // ---- fold this tile's 4 j's (rows q*4+reg) into per-i sums ----
        const int jbase = (w * 8 + jt) * 16 + q * 4;
        #pragma unroll
        for (int reg = 0; reg < 4; ++reg) {
            const float* pj = &spos[(jbase + reg) * 3];  // LDS broadcast
            const float dx = pix - pj[0];
            const float dy = piy - pj[1];
            const float dz = piz - pj[2];
            const float d2 = dx * dx + dy * dy + dz * dz;
            const float inv = d2 > 0.f ? rsqrtf(d2) : 0.f;   // i==j -> 0, matches ref
            const float wm = accm[reg] * inv;
            const float ws = accs[reg] * inv;
            am0 = fmaf(dx, wm, am0); am1 = fmaf(dy, wm, am1); am2 = fmaf(dz, wm, am2);
            al0 = fmaf(dx, ws, al0); al1 = fmaf(dy, ws, al1); al2 = fmaf(dz, ws, al2);
        }
    }

    // ---- reduce over the 4 q-groups (lanes r16, r16+16, r16+32, r16+48) ----
    am0 += __shfl_xor(am0, 16, 64); am0 += __shfl_xor(am0, 32, 64);
    am1 += __shfl_xor(am1, 16, 64); am1 += __shfl_xor(am1, 32, 64);
    am2 += __shfl_xor(am2, 16, 64); am2 += __shfl_xor(am2, 32, 64);
    al0 += __shfl_xor(al0, 16, 64); al0 += __shfl_xor(al0, 32, 64);
    al1 += __shfl_xor(al1, 16, 64); al1 += __shfl_xor(al1, 32, 64);
    al2 += __shfl_xor(al2, 16, 64); al2 += __shfl_xor(al2, 32, 64);

    // ---- cross-wave combine via LDS ----
    if (lane < 16) {
        float* p = wacc + (w * 16 + r16) * 6;
        p[0] = am0; p[1] = am1; p[2] = am2; p[3] = al0; p[4] = al1; p[5] = al2;
    }
    __syncthreads();
    if (t < 96) {
        float v = 0.f;
        #pragma unroll
        for (int ww = 0; ww < 8; ++ww) v += wacc[ww * 96 + t];
        fin[t] = v;
    }
    __syncthreads();

    // ---- inline tanh-normal tail for the 16 rows ----
    if (t < 16) {
        const int gi = b * NTOK + i0 + t;
        const float* v = fin + t * 6;
        float lp = 0.f;
        #pragma unroll
        for (int c = 0; c < 3; ++c) {
            const float als = fminf(fmaxf(v[3 + c], -20.f), 2.f);
            const float sd = expf(als);
            const float e = eps[gi * 3 + c];
            const float pre = fmaf(sd, e, v[c]);
            out[gi * 3 + c] = tanhf(pre) * 0.01f;
            const float t2 = 2.f * pre;
            lp += -0.5f * e * e - als - 2.3052328944f + softplusf(t2) + softplusf(-t2);
        }
        lp = red16(lp);   // lanes 0..15: full 16-lane row reduction
        if (t == 0) atomicAdd(out + 8 * NTOK * 3 + b, lp);
    }
}

extern "C" void kernel_launch(void* const* d_in, const int* in_sizes, int n_in,
                              void* d_out, int out_size, void* d_ws, size_t ws_size,
                              hipStream_t stream) {
    const float* kv = (const float*)d_in[0];
    const float* pos = (const float*)d_in[1];
    const float* eps = (const float*)d_in[2];
    float* out = (float*)d_out;
    unsigned short* frag = (unsigned short*)d_ws;   // 8 MiB

    prepass_kernel<<<dim3(1024), 256, 0, stream>>>(kv, frag, out);
    actor_kernel<<<dim3(512), 512, 0, stream>>>(frag, pos, eps, out);
}